// Round 3
// baseline (393.196 us; speedup 1.0000x reference)
//
#include <hip/hip_runtime.h>
#include <math.h>

// SmartDerivatives: out[b, a*3+dim] = (segment_sum(left * x[b,des]))^2
// Deterministic triu_indices(100,1) scatter: descriptor d = pair (i,j),
// row-major; 6 nonzeros per d: (i,0..2),(j,0..2). Index arrays never read.
//
// R3: R1/R2 were stuck at 110 us / 1.3 TB/s with VGPR_Count=16 -> per-wave
// serial load chains (compiler had no registers to keep loads in flight).
// Fix: __launch_bounds__(512,4) (128 VGPR budget) + fully batched loads
// (3 pairs/thread, all loads issued before any use) + frame split across
// 2 blocks to halve the chain; disjoint ws partials + tiny combine kernel.

#define N_ATOMS 100
#define D_DESC  4950            // 100*99/2
#define NPAIR   2475
#define BATCH   1024
#define NOUT    300
#define HALF0   1238            // pairs handled by sub-block 0 (sub 1: 1237)

__device__ __forceinline__ int rowstart(int i) {
    // sum_{k<i} (99-k) = i*(199-i)/2
    return (i * (2 * N_ATOMS - 1 - i)) >> 1;
}

__global__ __launch_bounds__(512, 4)
void sd_partial_kernel(const float* __restrict__ x,
                       const float* __restrict__ left,
                       float* __restrict__ ws) {
    __shared__ float acc[NOUT];
    const int b   = blockIdx.x >> 1;
    const int sub = blockIdx.x & 1;
    const int tid = threadIdx.x;

    for (int t = tid; t < NOUT; t += 512) acc[t] = 0.0f;
    __syncthreads();

    const float* __restrict__ xb = x    + (size_t)b * D_DESC;
    const float* __restrict__ lb = left + (size_t)b * D_DESC * 6;
    const float4* __restrict__ lb4 = (const float4*)lb;
    const float2* __restrict__ xb2 = (const float2*)xb;

    // ---- j-part: each thread owns up to 3 pairs; ALL loads issued upfront
    // (11 independent vmem ops ~ 168 B/lane in flight), then consumed.
    const int pstart = sub * HALF0;
    const int pend   = pstart + HALF0 - sub;     // 1238 or 1237 pairs
    int    pk[3];
    bool   vk[3];
    float4 q0[3], q1[3], q2[3];
    float2 xv[3];
    #pragma unroll
    for (int k = 0; k < 3; ++k) {
        pk[k] = pstart + tid + 512 * k;
        vk[k] = pk[k] < pend;
        if (vk[k]) {
            q0[k] = lb4[(size_t)pk[k] * 3 + 0];  // d0: l0 l1 l2 l3
            q1[k] = lb4[(size_t)pk[k] * 3 + 1];  // d0: l4 l5 | d1: l0 l1
            q2[k] = lb4[(size_t)pk[k] * 3 + 2];  // d1: l2 l3 l4 l5
            xv[k] = xb2[pk[k]];
        }
    }
    #pragma unroll
    for (int k = 0; k < 3; ++k) {
        if (vk[k]) {
            const int d0 = 2 * pk[k];
            // invert d0 -> row i of triu(100,1)
            const float fr = 39601.0f - 8.0f * (float)d0;   // 199^2 - 8d
            int i0 = (int)((199.0f - sqrtf(fr)) * 0.5f);
            while (rowstart(i0 + 1) <= d0) ++i0;   // fp-rounding fixup
            while (rowstart(i0) > d0) --i0;
            const int j0 = d0 - rowstart(i0) + i0 + 1;
            const int j1 = (j0 < N_ATOMS - 1) ? (j0 + 1) : (i0 + 2);
            atomicAdd(&acc[j0 * 3 + 0], q0[k].w * xv[k].x);
            atomicAdd(&acc[j0 * 3 + 1], q1[k].x * xv[k].x);
            atomicAdd(&acc[j0 * 3 + 2], q1[k].y * xv[k].x);
            atomicAdd(&acc[j1 * 3 + 0], q2[k].y * xv[k].y);
            atomicAdd(&acc[j1 * 3 + 1], q2[k].z * xv[k].y);
            atomicAdd(&acc[j1 * 3 + 2], q2[k].w * xv[k].y);
        }
    }

    // ---- i-part: rows a == sub (mod 2); one row per wave; both strided
    // iterations' loads batched (len <= 99 -> at most 2 per lane).
    const int wave = tid >> 6;
    const int lane = tid & 63;
    for (int r = wave; ; r += 8) {
        const int a = 2 * r + sub;
        if (a >= N_ATOMS - 1) break;
        const int rs  = rowstart(a);
        const int len = N_ATOMS - 1 - a;
        const int l0 = lane, l1 = lane + 64;
        float a00 = 0, a01 = 0, a02 = 0, x0 = 0;
        float a10 = 0, a11 = 0, a12 = 0, x1 = 0;
        if (l0 < len) {
            const float* lp = lb + (size_t)(rs + l0) * 6;
            a00 = lp[0]; a01 = lp[1]; a02 = lp[2]; x0 = xb[rs + l0];
        }
        if (l1 < len) {
            const float* lp = lb + (size_t)(rs + l1) * 6;
            a10 = lp[0]; a11 = lp[1]; a12 = lp[2]; x1 = xb[rs + l1];
        }
        float s0 = a00 * x0 + a10 * x1;
        float s1 = a01 * x0 + a11 * x1;
        float s2 = a02 * x0 + a12 * x1;
        #pragma unroll
        for (int off = 32; off > 0; off >>= 1) {
            s0 += __shfl_down(s0, off, 64);
            s1 += __shfl_down(s1, off, 64);
            s2 += __shfl_down(s2, off, 64);
        }
        if (lane == 0) {
            atomicAdd(&acc[a * 3 + 0], s0);
            atomicAdd(&acc[a * 3 + 1], s1);
            atomicAdd(&acc[a * 3 + 2], s2);
        }
    }

    __syncthreads();

    // disjoint partial write: ws[sub][b][0..299]
    float* __restrict__ wb = ws + ((size_t)sub * BATCH + b) * NOUT;
    for (int t = tid; t < NOUT; t += 512) wb[t] = acc[t];
}

// out = (ws0 + ws1)^2, float4-vectorized. 307200 floats = 76800 float4s.
__global__ __launch_bounds__(256)
void sd_combine_kernel(const float* __restrict__ ws, float* __restrict__ out) {
    const int idx = blockIdx.x * 256 + threadIdx.x;
    const float4 u = ((const float4*)ws)[idx];
    const float4 v = ((const float4*)(ws + (size_t)BATCH * NOUT))[idx];
    float4 o;
    o.x = u.x + v.x; o.x *= o.x;
    o.y = u.y + v.y; o.y *= o.y;
    o.z = u.z + v.z; o.z *= o.z;
    o.w = u.w + v.w; o.w *= o.w;
    ((float4*)out)[idx] = o;
}

extern "C" void kernel_launch(void* const* d_in, const int* in_sizes, int n_in,
                              void* d_out, int out_size, void* d_ws, size_t ws_size,
                              hipStream_t stream) {
    const float* x    = (const float*)d_in[0];   // [BATCH, D]
    const float* left = (const float*)d_in[1];   // [BATCH*D*6]
    float* ws  = (float*)d_ws;                   // 2 * 1024 * 300 floats = 2.46 MB
    float* out = (float*)d_out;                  // [BATCH, 300]

    sd_partial_kernel<<<BATCH * 2, 512, 0, stream>>>(x, left, ws);
    sd_combine_kernel<<<(BATCH * NOUT / 4) / 256, 256, 0, stream>>>(ws, out);
}

// Round 5
// 337.093 us; speedup vs baseline: 1.1664x; 1.1664x over previous
//
#include <hip/hip_runtime.h>

// SmartDerivatives: out[b, a*3+dim] = (segment_sum(left * x[b,des]))^2
// Deterministic triu_indices(100,1) scatter; index arrays never read.
//
// R4/R5: R1-R3 all pinned at ~110-120us / 1.3 TB/s regardless of load
// structure, occupancy, batching -> the invariant was ~15.2M lane-level LDS
// atomicAdds (theory: LDS atomic unit = the wall). This version has ZERO
// atomics: lane = output atom j; column sums (j-part) accumulate in
// registers while streaming rows; row sums (i-part) via DPP wave-reduction
// (VALU pipe, not LDS) with plain LDS stores (each row uniquely wave-owned).
// R5 fixes the R4 compile error: DPP ctrl/rmask must be constexpr ->
// template parameters.

#define N_ATOMS 100
#define D_DESC  4950
#define BATCH   1024
#define NOUT    300
#define NWAVES  8

// one DPP reduce step: v += dpp_shuffled(v), zero-filled OOB (old=0)
template<int CTRL, int RMASK>
__device__ __forceinline__ float dpp_step(float v) {
    int s = __builtin_amdgcn_update_dpp(0, __float_as_int(v), CTRL, RMASK, 0xf, true);
    return v + __int_as_float(s);
}
// full 64-lane sum; result valid in lane 63. VALU-pipe only.
__device__ __forceinline__ float wave_sum(float v) {
    v = dpp_step<0x111, 0xf>(v);   // row_shr:1
    v = dpp_step<0x112, 0xf>(v);   // row_shr:2
    v = dpp_step<0x114, 0xf>(v);   // row_shr:4
    v = dpp_step<0x118, 0xf>(v);   // row_shr:8  -> lane15 of each row16 = row sum
    v = dpp_step<0x142, 0xa>(v);   // row_bcast:15 into rows 1,3
    v = dpp_step<0x143, 0xc>(v);   // row_bcast:31 into rows 2,3 -> lane63 = total
    return v;
}

__global__ __launch_bounds__(512, 4)
void sd_kernel(const float* __restrict__ x,
               const float* __restrict__ left,
               float* __restrict__ out) {
    __shared__ float rowacc[NOUT];          // row (i-part) sums, uniquely written
    __shared__ float part[NWAVES][NOUT];    // per-wave column (j-part) partials
    const int b    = blockIdx.x;
    const int tid  = threadIdx.x;
    const int w    = tid >> 6;
    const int lane = tid & 63;

    for (int t = tid; t < NOUT; t += 512) rowacc[t] = 0.0f;  // atom 99 row = 0
    __syncthreads();

    const float* __restrict__ xb = x    + (size_t)b * D_DESC;
    const float* __restrict__ lb = left + (size_t)b * D_DESC * 6;

    // lane l owns output columns j=l (accA) and j=64+l (accB, l<36)
    float a0 = 0.f, a1 = 0.f, a2 = 0.f;
    float b0 = 0.f, b1 = 0.f, b2 = 0.f;

    for (int i = w; i < N_ATOMS - 1; i += NWAVES) {
        const int base = (i * (2 * N_ATOMS - 1 - i)) >> 1;   // rowstart(i)
        float s0 = 0.f, s1 = 0.f, s2 = 0.f;

        if (i < 63) {   // wave-uniform: columns j in [0,64) with j>i exist
            const int  j = lane;
            const bool v = j > i;
            const int  d = base + (v ? (j - i - 1) : 0);     // clamp: valid addr
            const float2* lp = (const float2*)(lb + (size_t)d * 6);
            const float2 c01 = lp[0];
            const float2 c23 = lp[1];
            const float2 c45 = lp[2];
            const float  xv  = xb[d];
            const float  m   = v ? xv : 0.f;
            s0 += c01.x * m;  s1 += c01.y * m;  s2 += c23.x * m;   // row i
            a0 += c23.y * m;  a1 += c45.x * m;  a2 += c45.y * m;   // col j
        }
        {   // columns j in [64,100)
            const int  j = 64 + lane;
            const bool v = (j < N_ATOMS) && (j > i);
            const int  d = base + (v ? (j - i - 1) : 0);
            const float2* lp = (const float2*)(lb + (size_t)d * 6);
            const float2 c01 = lp[0];
            const float2 c23 = lp[1];
            const float2 c45 = lp[2];
            const float  xv  = xb[d];
            const float  m   = v ? xv : 0.f;
            s0 += c01.x * m;  s1 += c01.y * m;  s2 += c23.x * m;
            b0 += c23.y * m;  b1 += c45.x * m;  b2 += c45.y * m;
        }

        s0 = wave_sum(s0);
        s1 = wave_sum(s1);
        s2 = wave_sum(s2);
        if (lane == 63) {           // row i owned by exactly one wave: plain store
            rowacc[i * 3 + 0] = s0;
            rowacc[i * 3 + 1] = s1;
            rowacc[i * 3 + 2] = s2;
        }
    }

    // per-wave column partials (plain stores, disjoint slices)
    part[w][lane * 3 + 0] = a0;
    part[w][lane * 3 + 1] = a1;
    part[w][lane * 3 + 2] = a2;
    if (lane < N_ATOMS - 64) {
        part[w][(64 + lane) * 3 + 0] = b0;
        part[w][(64 + lane) * 3 + 1] = b1;
        part[w][(64 + lane) * 3 + 2] = b2;
    }
    __syncthreads();

    // epilogue: total = rowsum + sum of 8 column partials; square; store
    float* __restrict__ ob = out + (size_t)b * NOUT;
    for (int t = tid; t < NOUT; t += 512) {
        float v = rowacc[t];
        #pragma unroll
        for (int q = 0; q < NWAVES; ++q) v += part[q][t];
        ob[t] = v * v;
    }
}

extern "C" void kernel_launch(void* const* d_in, const int* in_sizes, int n_in,
                              void* d_out, int out_size, void* d_ws, size_t ws_size,
                              hipStream_t stream) {
    const float* x    = (const float*)d_in[0];   // [BATCH, D]
    const float* left = (const float*)d_in[1];   // [BATCH*D*6]
    float* out = (float*)d_out;                  // [BATCH, 300]
    sd_kernel<<<BATCH, 512, 0, stream>>>(x, left, out);
}